// Round 3
// baseline (184.660 us; speedup 1.0000x reference)
//
#include <hip/hip_runtime.h>
#include <math.h>

#define NN   8192
#define EE   262144
#define CIN  64
#define DD   192      // IN_C*K = OUT_C*K
#define GG   64
#define NCLS 10
#define D3   576      // 3*DD
#define F1   384
#define F2   192
#define EPSB 1e-5f
#define NB   64        // edge-chunk blocks for count/scatter
#define EPB  (EE / NB) // 4096 edges per block

// order-preserving float<->uint key for atomicMax/Min pooling
__device__ __forceinline__ unsigned int fkey(float f) {
    unsigned int b = __float_as_uint(f);
    return b ^ (0x80000000u | (unsigned int)((int)b >> 31));
}
__device__ __forceinline__ float fdec(unsigned int k) {
    unsigned int b = k ^ ((k & 0x80000000u) ? 0x80000000u : 0xFFFFFFFFu);
    return __uint_as_float(b);
}

// ---- pack (0..323) + sigma (324) + gstart (325) + edge histogram (326..389)
//      + pooling-accumulator init (390)
__global__ __launch_bounds__(1024) void prep_kernel(const float* __restrict__ W,
    const float* __restrict__ u, const float* __restrict__ w1,
    const float* __restrict__ w2, const int* __restrict__ batch,
    const int* __restrict__ ei,
    float* __restrict__ sig, int* __restrict__ gstart,
    unsigned short* __restrict__ pcnt,
    float* __restrict__ Wp, float* __restrict__ Wp1, float* __restrict__ Wp2,
    int* __restrict__ pinit) {
    __shared__ int hist[NN];            // count blocks; aliased by sigma block
    int b = blockIdx.x, t = threadIdx.x;
    if (b < 324) {                      // ---- weight pack ----
        int idx = b * 1024 + t;
        if (idx < DD * DD) {
            int r = idx / DD, c = idx - r * DD;      // W element (out r, in c)
            float m = (c < CIN * ((r >> 6) + 1)) ? 1.f : 0.f;
            Wp[((c >> 2) * DD + r) * 4 + (c & 3)] = m * W[idx];
        } else if (idx < DD * DD + F1 * D3) {
            int i1 = idx - DD * DD;
            int tt = i1 / D3, k = i1 - tt * D3;
            Wp1[((k >> 2) * F1 + tt) * 4 + (k & 3)] = w1[i1];
        } else {
            int i2 = idx - DD * DD - F1 * D3;
            int tt = i2 / F1, k = i2 - tt * F1;
            Wp2[((k >> 2) * F2 + tt) * 4 + (k & 3)] = w2[i2];
        }
        return;
    }
    if (b == 325) {                     // ---- gstart (sorted-batch bounds) ----
        for (int i = t; i < NN; i += 1024) {
            int b0 = batch[i];
            int b1 = (i + 1 < NN) ? batch[i + 1] : GG;
            if (i == 0) { for (int g = 0; g <= b0; g++) gstart[g] = 0; }
            for (int g = b0 + 1; g <= b1; g++) gstart[g] = i + 1;
        }
        return;
    }
    if (b == 326 + NB) {                // ---- init pooling accumulators ----
        // Psum, Psq, Pmaxk zeroed (3*GG*DD words); Pmink = 0xFFFFFFFF
        int4* z = (int4*)pinit;
        for (int i = t; i < 3 * GG * DD / 4; i += 1024) z[i] = make_int4(0, 0, 0, 0);
        int4* m = (int4*)(pinit + 3 * GG * DD);
        for (int i = t; i < GG * DD / 4; i += 1024) m[i] = make_int4(-1, -1, -1, -1);
        return;
    }
    if (b >= 326) {                     // ---- per-chunk edge histogram ----
        int cb = b - 326;               // chunk id 0..NB-1
        int4* hz = (int4*)hist;
        for (int i = t; i < NN / 4; i += 1024) hz[i] = make_int4(0, 0, 0, 0);
        __syncthreads();
        int e0 = cb * EPB;
        for (int i = t; i < EPB; i += 1024) atomicAdd(&hist[ei[e0 + i]], 1);
        __syncthreads();
        const int2* h2 = (const int2*)hist;
        ushort2* q2 = (ushort2*)&pcnt[cb * NN];
        for (int i = t; i < NN / 2; i += 1024) {
            int2 h = h2[i];
            q2[i] = make_ushort2((unsigned short)h.x, (unsigned short)h.y);
        }
        return;
    }
    // ---- sigma (block 324; LDS aliases hist) ----
    float* vp  = (float*)hist;          // 768 floats
    float* vsh = vp + 768;              // 192 floats
    float* red = vsh + DD;              // 1024 floats
    if (t < 768) {
        int c = t >> 2, j = t & 3;
        float s = 0.f;
        const float* Wc = W + c;
        for (int i = j * 48; i < j * 48 + 48; i++) s += Wc[i * DD] * u[i];
        vp[t] = s;
    }
    __syncthreads();
    float vv = 0.f;
    if (t < DD) {
        float v = vp[4 * t] + vp[4 * t + 1] + vp[4 * t + 2] + vp[4 * t + 3];
        vsh[t] = v;
        vv = v * v;
    }
    red[t] = vv;
    __syncthreads();
    for (int off = 512; off > 0; off >>= 1) {
        if (t < off) red[t] += red[t + off];
        __syncthreads();
    }
    float norm = sqrtf(red[0]) + 1e-12f;
    __syncthreads();
    float a = 0.f;
    for (int idx = t; idx < DD * DD; idx += 1024) {
        int r = idx / DD, c = idx - r * DD;
        a += u[r] * W[idx] * vsh[c];
    }
    red[t] = a;
    __syncthreads();
    for (int off = 512; off > 0; off >>= 1) {
        if (t < off) red[t] += red[t + off];
        __syncthreads();
    }
    if (t == 0) sig[0] = norm / red[0];      // inv_sigma = norm / S
}

// ---- per-row reduce + exclusive scan over blocks: off[b][i], deg[i], dinv[i]
__global__ __launch_bounds__(256) void offs_kernel(unsigned short* __restrict__ pcnt,
                                                   int* __restrict__ deg,
                                                   float* __restrict__ dinv) {
    int i = blockIdx.x * 256 + threadIdx.x;   // grid = NN/256
    int run = 0;
#pragma unroll
    for (int b = 0; b < NB; b++) {
        int v = pcnt[b * NN + i];
        pcnt[b * NN + i] = (unsigned short)run;   // becomes off[b][i] (fits u16)
        run += v;
    }
    deg[i] = run;
    dinv[i] = (run > 0) ? rsqrtf((float)run) : 0.f;
}

// ---- CSR build: per-block LDS scan of deg -> cursors; block 0 -> rowptr ----
__global__ __launch_bounds__(1024) void scatter_kernel(const int* __restrict__ ei,
                                                       const int* __restrict__ deg,
                                                       const unsigned short* __restrict__ off,
                                                       int* __restrict__ rowptr,
                                                       unsigned short* __restrict__ csr_col) {
    __shared__ int cur[NN];
    __shared__ int temp[1024];
    int b = blockIdx.x, t = threadIdx.x;
    int base = t * 8;
    int d[8], l[8];
    {
        const int4 a4 = *(const int4*)&deg[base];
        const int4 b4 = *(const int4*)&deg[base + 4];
        d[0] = a4.x; d[1] = a4.y; d[2] = a4.z; d[3] = a4.w;
        d[4] = b4.x; d[5] = b4.y; d[6] = b4.z; d[7] = b4.w;
    }
    int run = 0;
#pragma unroll
    for (int j = 0; j < 8; j++) { l[j] = run; run += d[j]; }
    temp[t] = run;
    __syncthreads();
    for (int o = 1; o < 1024; o <<= 1) {
        int v = (t >= o) ? temp[t - o] : 0;
        __syncthreads();
        temp[t] += v;
        __syncthreads();
    }
    int prefix = (t > 0) ? temp[t - 1] : 0;
    {   // unpack 8 u16 chunk-offsets (16B aligned contiguous load)
        const unsigned short* ob = &off[b * NN];
        int4 opk = *(const int4*)(ob + base);
        cur[base + 0] = prefix + l[0] + (opk.x & 0xFFFF);
        cur[base + 1] = prefix + l[1] + (int)((unsigned)opk.x >> 16);
        cur[base + 2] = prefix + l[2] + (opk.y & 0xFFFF);
        cur[base + 3] = prefix + l[3] + (int)((unsigned)opk.y >> 16);
        cur[base + 4] = prefix + l[4] + (opk.z & 0xFFFF);
        cur[base + 5] = prefix + l[5] + (int)((unsigned)opk.z >> 16);
        cur[base + 6] = prefix + l[6] + (opk.w & 0xFFFF);
        cur[base + 7] = prefix + l[7] + (int)((unsigned)opk.w >> 16);
    }
    if (b == 0) {
#pragma unroll
        for (int j = 0; j < 8; j++) rowptr[base + j] = prefix + l[j];
        if (t == 1023) rowptr[NN] = temp[1023];
    }
    __syncthreads();
    int e0 = b * EPB;
    for (int i = t; i < EPB; i += 1024) {
        int r = ei[e0 + i];
        int c = ei[EE + e0 + i];
        int pos = atomicAdd(&cur[r], 1);       // LDS atomic
        csr_col[pos] = (unsigned short)c;
    }
}

// pass 1: Hx1 = L @ x, one wave per row, 4-way unrolled edge loop.
// Hx1 is compact [N,64] (x itself is NOT copied; gemm reads x directly).
__global__ __launch_bounds__(256) void spmm1_kernel(const float* __restrict__ x,
    const int* __restrict__ rowptr, const unsigned short* __restrict__ col,
    const float* __restrict__ dinv, float* __restrict__ Hx1) {
    int idx = blockIdx.x * 256 + threadIdx.x;   // N*64 threads
    int row = idx >> 6;
    int lane = idx & 63;
    int s = rowptr[row], e = rowptr[row + 1];
    float acc0 = 0.f, acc1 = 0.f, acc2 = 0.f, acc3 = 0.f;
    int p = s;
    for (; p + 3 < e; p += 4) {
        int c0 = col[p], c1 = col[p + 1], c2 = col[p + 2], c3 = col[p + 3];
        acc0 += dinv[c0] * x[c0 * 64 + lane];
        acc1 += dinv[c1] * x[c1 * 64 + lane];
        acc2 += dinv[c2] * x[c2 * 64 + lane];
        acc3 += dinv[c3] * x[c3 * 64 + lane];
    }
    for (; p < e; p++) {
        int c = col[p];
        acc0 += dinv[c] * x[c * 64 + lane];
    }
    float acc = (acc0 + acc1) + (acc2 + acc3);
    float self = x[row * 64 + lane];
    Hx1[row * 64 + lane] = self - dinv[row] * acc;
}

// ------ FUSED: L^2 x (gather) + H = inv_sigma*(Hcat @ Wmask^T)+b + pooling.
// 16 rows/block, 384 threads (6 waves).
// Phase 1: x rows -> LDS cols 0..63, Hx1 rows -> LDS cols 64..127.
// Phase 2: one wave per row (round-robin), gather L@Hx1 -> LDS cols 128..191.
//          (Lx self-term comes from LDS for free.)
// Phase 3: GEMM, half 0 -> rows 0-7, half 1 -> rows 8-15 (192 channels each).
// Phase 4: segmented pooling partials via device atomics.
// Neither Hcat nor H ever touches global memory.
__global__ __launch_bounds__(384) void sgp_kernel(const float* __restrict__ x,
    const float* __restrict__ Hx1,
    const int* __restrict__ rowptr, const unsigned short* __restrict__ col,
    const float* __restrict__ dinv,
    const float* __restrict__ Wp, const float* __restrict__ bias,
    const float* __restrict__ sig, const int* __restrict__ batch,
    float* __restrict__ Psum, float* __restrict__ Psq,
    unsigned int* __restrict__ Pmaxk, unsigned int* __restrict__ Pmink) {
    __shared__ float hs[16 * DD];      // 12 KB
    __shared__ int bb[16];
    int t = threadIdx.x;
    int n0 = blockIdx.x * 16;
    // ---- phase 1: stage x and Hx1 rows (512 float4 loads over 384 threads)
    for (int i = t; i < 512; i += 384) {
        int r = i >> 5, q = i & 31;                 // 32 float4s per row (cols 0..127)
        float4 v = (q < 16) ? ((const float4*)x)[(n0 + r) * 16 + q]
                            : ((const float4*)Hx1)[(n0 + r) * 16 + (q - 16)];
        *(float4*)&hs[r * DD + q * 4] = v;
    }
    if (t < 16) bb[t] = batch[n0 + t];
    __syncthreads();
    // ---- phase 2: L^2 x for the 16 rows
    {
        int lane = t & 63, wv = t >> 6;             // 6 waves
        for (int r = wv; r < 16; r += 6) {
            int row = n0 + r;
            int s = rowptr[row], e = rowptr[row + 1];
            float acc0 = 0.f, acc1 = 0.f, acc2 = 0.f, acc3 = 0.f;
            int p = s;
            for (; p + 3 < e; p += 4) {
                int c0 = col[p], c1 = col[p + 1], c2 = col[p + 2], c3 = col[p + 3];
                acc0 += dinv[c0] * Hx1[c0 * 64 + lane];
                acc1 += dinv[c1] * Hx1[c1 * 64 + lane];
                acc2 += dinv[c2] * Hx1[c2 * 64 + lane];
                acc3 += dinv[c3] * Hx1[c3 * 64 + lane];
            }
            for (; p < e; p++) {
                int c = col[p];
                acc0 += dinv[c] * Hx1[c * 64 + lane];
            }
            float acc = (acc0 + acc1) + (acc2 + acc3);
            float self = hs[r * DD + 64 + lane];    // Lx self-term from LDS
            hs[r * DD + 128 + lane] = self - dinv[row] * acc;
        }
    }
    __syncthreads();
    // ---- phase 3: GEMM (two halves of 192 output channels, 8 rows each)
    int half = t / 192;               // wave-uniform (waves 0-2 vs 3-5)
    int ch = t - half * 192;          // output channel
    int r0 = half * 8;
    float acc[8];
#pragma unroll
    for (int r = 0; r < 8; r++) acc[r] = 0.f;
    const float4* Wp4 = (const float4*)Wp;
    const float* hb = &hs[r0 * DD];
    for (int k4 = 0; k4 < DD / 4; k4++) {
        float4 w = Wp4[k4 * DD + ch];
#pragma unroll
        for (int r = 0; r < 8; r++) {
            const float4 h = *(const float4*)&hb[r * DD + k4 * 4];
            acc[r] += h.x * w.x + h.y * w.y + h.z * w.z + h.w * w.w;
        }
    }
    float inv_sigma = sig[0];
    float bv = bias[ch];
    // ---- phase 4: segmented pooling (segment branch is block-uniform)
    int gcur = bb[r0];
    float sum = 0.f, sq = 0.f, mn = INFINITY, mx = -INFINITY;
#pragma unroll
    for (int r = 0; r < 8; r++) {
        float v = inv_sigma * acc[r] + bv;
        int g = bb[r0 + r];
        if (g != gcur) {
            atomicAdd(&Psum[gcur * DD + ch], sum);
            atomicAdd(&Psq[gcur * DD + ch], sq);
            atomicMax(&Pmaxk[gcur * DD + ch], fkey(mx));
            atomicMin(&Pmink[gcur * DD + ch], fkey(mn));
            sum = 0.f; sq = 0.f; mn = INFINITY; mx = -INFINITY; gcur = g;
        }
        sum += v; sq += v * v;
        mn = fminf(mn, v); mx = fmaxf(mx, v);
    }
    atomicAdd(&Psum[gcur * DD + ch], sum);
    atomicAdd(&Psq[gcur * DD + ch], sq);
    atomicMax(&Pmaxk[gcur * DD + ch], fkey(mx));
    atomicMin(&Pmink[gcur * DD + ch], fkey(mn));
}

// ------ BN1 finalize (fused, butterfly) + Hg + BN2: block=column, lane=graph
__global__ __launch_bounds__(64) void hg_kernel(
    const float* __restrict__ Psum, const float* __restrict__ Psq,
    const unsigned int* __restrict__ Pmaxk, const unsigned int* __restrict__ Pmink,
    const int* __restrict__ gstart,
    const float* __restrict__ g1, const float* __restrict__ be1,
    const float* __restrict__ g2, const float* __restrict__ be2,
    float* __restrict__ Hg) {
    int t = blockIdx.x;          // column 0..D3-1
    int g = threadIdx.x;         // graph 0..63
    int f = t / DD, c = t - f * DD;  // f: 0=avg 1=sum 2=max (block-uniform)
    float Sg = Psum[g * DD + c];
    float Qg = Psq[g * DD + c];
    float S = Sg, Q = Qg;
    for (int off = 32; off > 0; off >>= 1) {
        S += __shfl_xor(S, off);
        Q += __shfl_xor(Q, off);
    }
    float mu = S * (1.f / (float)NN);
    float var = Q * (1.f / (float)NN) - mu * mu;
    float sc = g1[c] * rsqrtf(var + EPSB);
    float bb = be1[c];
    float v;
    if (f == 2) {
        float mx = fdec(Pmaxk[g * DD + c]);
        float mn = fdec(Pmink[g * DD + c]);
        float raw = (sc >= 0.f) ? mx : mn;
        v = sc * (raw - mu) + bb;
    } else {
        float nf = (float)(gstart[g + 1] - gstart[g]);
        float hsum = sc * (Sg - nf * mu) + nf * bb;
        v = (f == 0) ? hsum / fmaxf(nf, 1.f) : hsum;
    }
    float s2 = v, ss2 = v * v;
    for (int off = 32; off > 0; off >>= 1) {
        s2 += __shfl_xor(s2, off);
        ss2 += __shfl_xor(ss2, off);
    }
    float m2 = s2 * (1.f / (float)GG);
    float var2 = ss2 * (1.f / (float)GG) - m2 * m2;
    float sc2 = g2[t] * rsqrtf(var2 + EPSB);
    Hg[g * D3 + t] = sc2 * (v - m2) + be2[t];
}

// ------ funnel head + log_softmax, ONE graph per block (64 blocks) ----------
__global__ __launch_bounds__(F1) void funnel_kernel(const float* __restrict__ Hg,
    const float* __restrict__ Wp1, const float* __restrict__ b1,
    const float* __restrict__ Wp2, const float* __restrict__ b2,
    const float* __restrict__ w3, const float* __restrict__ b3,
    float* __restrict__ out) {
    __shared__ float hg[D3];
    __shared__ float x1[F1];
    __shared__ float x2[F2];
    __shared__ float lg[NCLS];
    __shared__ float s_lse;
    int g = blockIdx.x, t = threadIdx.x;
    for (int i = t; i < D3; i += F1) hg[i] = Hg[g * D3 + i];
    __syncthreads();
    {
        float a = b1[t];
        const float4* W4 = (const float4*)Wp1;
        for (int k4 = 0; k4 < D3 / 4; k4++) {
            float4 w = W4[k4 * F1 + t];                 // coalesced
            const float4 h = *(const float4*)&hg[k4 * 4]; // broadcast
            a += w.x * h.x + w.y * h.y + w.z * h.z + w.w * h.w;
        }
        x1[t] = fmaxf(a, 0.f);
    }
    __syncthreads();
    if (t < F2) {
        float a = b2[t];
        const float4* W4 = (const float4*)Wp2;
        for (int k4 = 0; k4 < F1 / 4; k4++) {
            float4 w = W4[k4 * F2 + t];                 // coalesced
            const float4 h = *(const float4*)&x1[k4 * 4]; // broadcast
            a += w.x * h.x + w.y * h.y + w.z * h.z + w.w * h.w;
        }
        x2[t] = fmaxf(a, 0.f);
    }
    __syncthreads();
    if (t < NCLS) {
        float a = b3[t];
        const float4* wr = (const float4*)&w3[t * F2];
        const float4* h4 = (const float4*)x2;
        for (int k = 0; k < F2 / 4; k++) {
            float4 w = wr[k], h = h4[k];
            a += w.x * h.x + w.y * h.y + w.z * h.z + w.w * h.w;
        }
        lg[t] = a;
    }
    __syncthreads();
    if (t == 0) {
        float m = lg[0];
        for (int i = 1; i < NCLS; i++) m = fmaxf(m, lg[i]);
        float se = 0.f;
        for (int i = 0; i < NCLS; i++) se += expf(lg[i] - m);
        s_lse = m + logf(se);
    }
    __syncthreads();
    if (t < NCLS) out[g * NCLS + t] = lg[t] - s_lse;
}

// ---------------- launcher ----------------

extern "C" void kernel_launch(void* const* d_in, const int* in_sizes, int n_in,
                              void* d_out, int out_size, void* d_ws, size_t ws_size,
                              hipStream_t stream) {
    (void)in_sizes; (void)n_in; (void)out_size; (void)ws_size;
    const float* x     = (const float*)d_in[0];
    const int*   ei    = (const int*)d_in[1];    // int32 on device (harness contract)
    const int*   batch = (const int*)d_in[2];
    const float* W     = (const float*)d_in[3];
    const float* b     = (const float*)d_in[4];
    const float* u     = (const float*)d_in[5];
    const float* g1    = (const float*)d_in[6];
    const float* be1   = (const float*)d_in[7];
    const float* g2    = (const float*)d_in[8];
    const float* be2   = (const float*)d_in[9];
    const float* w1    = (const float*)d_in[10];
    const float* b1    = (const float*)d_in[11];
    const float* w2    = (const float*)d_in[12];
    const float* b2    = (const float*)d_in[13];
    const float* w3    = (const float*)d_in[14];
    const float* b3    = (const float*)d_in[15];
    float* out = (float*)d_out;
    char*  ws  = (char*)d_ws;

    // ---- workspace layout (bytes), ~5.4 MB ----
    int*            gstart  = (int*)(ws + 0);            //     512 (65 ints)
    int*            rowptr  = (int*)(ws + 512);          //   33024
    int*            deg     = (int*)(ws + 33536);        //   32768
    float*          dinv    = (float*)(ws + 66304);      //   32768
    float*          sig     = (float*)(ws + 99072);      //     256
    float*          Wp      = (float*)(ws + 99328);      //  147456
    float*          Psum    = (float*)(ws + 246784);     //   49152 (GG*DD)
    float*          Psq     = (float*)(ws + 295936);     //   49152
    unsigned int*   Pmaxk   = (unsigned int*)(ws + 345088); // 49152
    unsigned int*   Pmink   = (unsigned int*)(ws + 394240); // 49152
    float*          Hg      = (float*)(ws + 443392);     //  147456
    unsigned short* csr_col = (unsigned short*)(ws + 590848); // 524288
    float*          Wp1     = (float*)(ws + 1115136);    //  884736
    float*          Wp2     = (float*)(ws + 1999872);    //  294912
    unsigned short* pcnt    = (unsigned short*)(ws + 2294784); // 1048576 (u16)
    float*          Hx1     = (float*)(ws + 3343360);    // 2097152 -> end 5440512

    prep_kernel<<<326 + NB + 1, 1024, 0, stream>>>(W, u, w1, w2, batch, ei,
                                                   sig, gstart, pcnt, Wp, Wp1, Wp2,
                                                   (int*)Psum);
    offs_kernel<<<NN / 256, 256, 0, stream>>>(pcnt, deg, dinv);
    scatter_kernel<<<NB, 1024, 0, stream>>>(ei, deg, pcnt, rowptr, csr_col);
    // pass 1: Hx1 = L @ x  (compact [N,64])
    spmm1_kernel<<<NN * 64 / 256, 256, 0, stream>>>(x, rowptr, csr_col, dinv, Hx1);
    // fused: L^2 x gather + masked GEMM + triple pooling
    sgp_kernel<<<NN / 16, 384, 0, stream>>>(x, Hx1, rowptr, csr_col, dinv,
                                            Wp, b, sig, batch,
                                            Psum, Psq, Pmaxk, Pmink);
    hg_kernel<<<D3, 64, 0, stream>>>(Psum, Psq, Pmaxk, Pmink, gstart, g1, be1, g2, be2, Hg);
    funnel_kernel<<<GG, F1, 0, stream>>>(Hg, Wp1, b1, Wp2, b2, w3, b3, out);
}

// Round 4
// 179.826 us; speedup vs baseline: 1.0269x; 1.0269x over previous
//
#include <hip/hip_runtime.h>
#include <math.h>

#define NN   8192
#define EE   262144
#define CIN  64
#define DD   192      // IN_C*K = OUT_C*K
#define GG   64
#define NCLS 10
#define D3   576      // 3*DD
#define F1   384
#define F2   192
#define EPSB 1e-5f
#define NB   64        // edge-chunk blocks for count/scatter
#define EPB  (EE / NB) // 4096 edges per block

// order-preserving float<->uint key for atomicMax/Min pooling
__device__ __forceinline__ unsigned int fkey(float f) {
    unsigned int b = __float_as_uint(f);
    return b ^ (0x80000000u | (unsigned int)((int)b >> 31));
}
__device__ __forceinline__ float fdec(unsigned int k) {
    unsigned int b = k ^ ((k & 0x80000000u) ? 0x80000000u : 0xFFFFFFFFu);
    return __uint_as_float(b);
}

// ---- pack (0..323) + sigma (324) + gstart (325) + edge histogram (326..389)
//      + pooling-accumulator init (390)
__global__ __launch_bounds__(1024) void prep_kernel(const float* __restrict__ W,
    const float* __restrict__ u, const float* __restrict__ w1,
    const float* __restrict__ w2, const int* __restrict__ batch,
    const int* __restrict__ ei,
    float* __restrict__ sig, int* __restrict__ gstart,
    unsigned short* __restrict__ pcnt,
    float* __restrict__ Wp, float* __restrict__ Wp1, float* __restrict__ Wp2,
    int* __restrict__ pinit) {
    __shared__ int hist[NN];            // count blocks; aliased by sigma block
    int b = blockIdx.x, t = threadIdx.x;
    if (b < 324) {                      // ---- weight pack ----
        int idx = b * 1024 + t;
        if (idx < DD * DD) {
            int r = idx / DD, c = idx - r * DD;      // W element (out r, in c)
            float m = (c < CIN * ((r >> 6) + 1)) ? 1.f : 0.f;
            Wp[((c >> 2) * DD + r) * 4 + (c & 3)] = m * W[idx];
        } else if (idx < DD * DD + F1 * D3) {
            int i1 = idx - DD * DD;
            int tt = i1 / D3, k = i1 - tt * D3;
            Wp1[((k >> 2) * F1 + tt) * 4 + (k & 3)] = w1[i1];
        } else {
            int i2 = idx - DD * DD - F1 * D3;
            int tt = i2 / F1, k = i2 - tt * F1;
            Wp2[((k >> 2) * F2 + tt) * 4 + (k & 3)] = w2[i2];
        }
        return;
    }
    if (b == 325) {                     // ---- gstart (sorted-batch bounds) ----
        for (int i = t; i < NN; i += 1024) {
            int b0 = batch[i];
            int b1 = (i + 1 < NN) ? batch[i + 1] : GG;
            if (i == 0) { for (int g = 0; g <= b0; g++) gstart[g] = 0; }
            for (int g = b0 + 1; g <= b1; g++) gstart[g] = i + 1;
        }
        return;
    }
    if (b == 326 + NB) {                // ---- init pooling accumulators ----
        // Psum, Psq, Pmaxk zeroed (3*GG*DD words); Pmink = 0xFFFFFFFF
        int4* z = (int4*)pinit;
        for (int i = t; i < 3 * GG * DD / 4; i += 1024) z[i] = make_int4(0, 0, 0, 0);
        int4* m = (int4*)(pinit + 3 * GG * DD);
        for (int i = t; i < GG * DD / 4; i += 1024) m[i] = make_int4(-1, -1, -1, -1);
        return;
    }
    if (b >= 326) {                     // ---- per-chunk edge histogram ----
        int cb = b - 326;               // chunk id 0..NB-1
        int4* hz = (int4*)hist;
        for (int i = t; i < NN / 4; i += 1024) hz[i] = make_int4(0, 0, 0, 0);
        __syncthreads();
        int e0 = cb * EPB;
        for (int i = t; i < EPB; i += 1024) atomicAdd(&hist[ei[e0 + i]], 1);
        __syncthreads();
        const int2* h2 = (const int2*)hist;
        ushort2* q2 = (ushort2*)&pcnt[cb * NN];
        for (int i = t; i < NN / 2; i += 1024) {
            int2 h = h2[i];
            q2[i] = make_ushort2((unsigned short)h.x, (unsigned short)h.y);
        }
        return;
    }
    // ---- sigma (block 324; LDS aliases hist) ----
    float* vp  = (float*)hist;          // 768 floats
    float* vsh = vp + 768;              // 192 floats
    float* red = vsh + DD;              // 1024 floats
    if (t < 768) {
        int c = t >> 2, j = t & 3;
        float s = 0.f;
        const float* Wc = W + c;
        for (int i = j * 48; i < j * 48 + 48; i++) s += Wc[i * DD] * u[i];
        vp[t] = s;
    }
    __syncthreads();
    float vv = 0.f;
    if (t < DD) {
        float v = vp[4 * t] + vp[4 * t + 1] + vp[4 * t + 2] + vp[4 * t + 3];
        vsh[t] = v;
        vv = v * v;
    }
    red[t] = vv;
    __syncthreads();
    for (int off = 512; off > 0; off >>= 1) {
        if (t < off) red[t] += red[t + off];
        __syncthreads();
    }
    float norm = sqrtf(red[0]) + 1e-12f;
    __syncthreads();
    float a = 0.f;
    for (int idx = t; idx < DD * DD; idx += 1024) {
        int r = idx / DD, c = idx - r * DD;
        a += u[r] * W[idx] * vsh[c];
    }
    red[t] = a;
    __syncthreads();
    for (int off = 512; off > 0; off >>= 1) {
        if (t < off) red[t] += red[t + off];
        __syncthreads();
    }
    if (t == 0) sig[0] = norm / red[0];      // inv_sigma = norm / S
}

// ---- per-row reduce + exclusive scan over blocks: off[b][i], deg[i], dinv[i]
__global__ __launch_bounds__(256) void offs_kernel(unsigned short* __restrict__ pcnt,
                                                   int* __restrict__ deg,
                                                   float* __restrict__ dinv) {
    int i = blockIdx.x * 256 + threadIdx.x;   // grid = NN/256
    int run = 0;
#pragma unroll
    for (int b = 0; b < NB; b++) {
        int v = pcnt[b * NN + i];
        pcnt[b * NN + i] = (unsigned short)run;   // becomes off[b][i] (fits u16)
        run += v;
    }
    deg[i] = run;
    dinv[i] = (run > 0) ? rsqrtf((float)run) : 0.f;
}

// ---- CSR build: per-block LDS scan of deg -> cursors; block 0 -> rowptr ----
__global__ __launch_bounds__(1024) void scatter_kernel(const int* __restrict__ ei,
                                                       const int* __restrict__ deg,
                                                       const unsigned short* __restrict__ off,
                                                       int* __restrict__ rowptr,
                                                       unsigned short* __restrict__ csr_col) {
    __shared__ int cur[NN];
    __shared__ int temp[1024];
    int b = blockIdx.x, t = threadIdx.x;
    int base = t * 8;
    int d[8], l[8];
    {
        const int4 a4 = *(const int4*)&deg[base];
        const int4 b4 = *(const int4*)&deg[base + 4];
        d[0] = a4.x; d[1] = a4.y; d[2] = a4.z; d[3] = a4.w;
        d[4] = b4.x; d[5] = b4.y; d[6] = b4.z; d[7] = b4.w;
    }
    int run = 0;
#pragma unroll
    for (int j = 0; j < 8; j++) { l[j] = run; run += d[j]; }
    temp[t] = run;
    __syncthreads();
    for (int o = 1; o < 1024; o <<= 1) {
        int v = (t >= o) ? temp[t - o] : 0;
        __syncthreads();
        temp[t] += v;
        __syncthreads();
    }
    int prefix = (t > 0) ? temp[t - 1] : 0;
    {   // unpack 8 u16 chunk-offsets (16B aligned contiguous load)
        const unsigned short* ob = &off[b * NN];
        int4 opk = *(const int4*)(ob + base);
        cur[base + 0] = prefix + l[0] + (opk.x & 0xFFFF);
        cur[base + 1] = prefix + l[1] + (int)((unsigned)opk.x >> 16);
        cur[base + 2] = prefix + l[2] + (opk.y & 0xFFFF);
        cur[base + 3] = prefix + l[3] + (int)((unsigned)opk.y >> 16);
        cur[base + 4] = prefix + l[4] + (opk.z & 0xFFFF);
        cur[base + 5] = prefix + l[5] + (int)((unsigned)opk.z >> 16);
        cur[base + 6] = prefix + l[6] + (opk.w & 0xFFFF);
        cur[base + 7] = prefix + l[7] + (int)((unsigned)opk.w >> 16);
    }
    if (b == 0) {
#pragma unroll
        for (int j = 0; j < 8; j++) rowptr[base + j] = prefix + l[j];
        if (t == 1023) rowptr[NN] = temp[1023];
    }
    __syncthreads();
    int e0 = b * EPB;
    for (int i = t; i < EPB; i += 1024) {
        int r = ei[e0 + i];
        int c = ei[EE + e0 + i];
        int pos = atomicAdd(&cur[r], 1);       // LDS atomic
        csr_col[pos] = (unsigned short)c;
    }
}

// out = in_row - dinv[row] * sum_e dinv[col_e] * in[col_e]
// One wave per row, compact [N,64] in/out, 4-way unrolled edge loop.
// High occupancy (8 waves/SIMD) is what hides the gather latency — fusing
// this into the GEMM block (round 3) dropped occupancy to 25% and cost 4x.
__global__ __launch_bounds__(256) void spmm_kernel(const float* __restrict__ in,
    const int* __restrict__ rowptr, const unsigned short* __restrict__ col,
    const float* __restrict__ dinv, float* __restrict__ outb) {
    int idx = blockIdx.x * 256 + threadIdx.x;   // N*64 threads
    int row = idx >> 6;
    int lane = idx & 63;
    int s = rowptr[row], e = rowptr[row + 1];
    float acc0 = 0.f, acc1 = 0.f, acc2 = 0.f, acc3 = 0.f;
    int p = s;
    for (; p + 3 < e; p += 4) {
        int c0 = col[p], c1 = col[p + 1], c2 = col[p + 2], c3 = col[p + 3];
        acc0 += dinv[c0] * in[c0 * 64 + lane];
        acc1 += dinv[c1] * in[c1 * 64 + lane];
        acc2 += dinv[c2] * in[c2 * 64 + lane];
        acc3 += dinv[c3] * in[c3 * 64 + lane];
    }
    for (; p < e; p++) {
        int c = col[p];
        acc0 += dinv[c] * in[c * 64 + lane];
    }
    float acc = (acc0 + acc1) + (acc2 + acc3);
    float self = in[row * 64 + lane];
    outb[row * 64 + lane] = self - dinv[row] * acc;
}

// ------ H = inv_sigma * ([x|Hx1|Hx2] @ Wmask^T) + b, FUSED with pooling.
// 16 rows/block, 384 threads: half 0 -> rows 0-7, half 1 -> rows 8-15.
// Stages the three compact [N,64] buffers into one [16][192] LDS tile.
// H never touches global memory (pool was its only consumer).
__global__ __launch_bounds__(384) void gemm_pool_kernel(const float* __restrict__ x,
    const float* __restrict__ Hx1, const float* __restrict__ Hx2,
    const float* __restrict__ Wp, const float* __restrict__ bias,
    const float* __restrict__ sig, const int* __restrict__ batch,
    float* __restrict__ Psum, float* __restrict__ Psq,
    unsigned int* __restrict__ Pmaxk, unsigned int* __restrict__ Pmink) {
    __shared__ float hs[16 * DD];      // 12 KB
    __shared__ int bb[16];
    int t = threadIdx.x;
    int n0 = blockIdx.x * 16;
    // stage: 16 rows x 48 float4 (x cols 0..63, Hx1 64..127, Hx2 128..191)
    for (int i = t; i < 768; i += 384) {
        int r = i / 48, q = i - r * 48;
        float4 v;
        if (q < 16)      v = ((const float4*)x)[(n0 + r) * 16 + q];
        else if (q < 32) v = ((const float4*)Hx1)[(n0 + r) * 16 + (q - 16)];
        else             v = ((const float4*)Hx2)[(n0 + r) * 16 + (q - 32)];
        *(float4*)&hs[r * DD + q * 4] = v;
    }
    if (t < 16) bb[t] = batch[n0 + t];
    __syncthreads();
    int half = t / 192;               // wave-uniform (waves 0-2 vs 3-5)
    int ch = t - half * 192;          // output channel
    int r0 = half * 8;
    float acc[8];
#pragma unroll
    for (int r = 0; r < 8; r++) acc[r] = 0.f;
    const float4* Wp4 = (const float4*)Wp;
    const float* hb = &hs[r0 * DD];
    for (int k4 = 0; k4 < DD / 4; k4++) {
        float4 w = Wp4[k4 * DD + ch];
#pragma unroll
        for (int r = 0; r < 8; r++) {
            const float4 h = *(const float4*)&hb[r * DD + k4 * 4];
            acc[r] += h.x * w.x + h.y * w.y + h.z * w.z + h.w * w.w;
        }
    }
    float inv_sigma = sig[0];
    float bv = bias[ch];
    // segmented pooling over this half's 8 rows (segment branch is block-uniform)
    int gcur = bb[r0];
    float sum = 0.f, sq = 0.f, mn = INFINITY, mx = -INFINITY;
#pragma unroll
    for (int r = 0; r < 8; r++) {
        float v = inv_sigma * acc[r] + bv;
        int g = bb[r0 + r];
        if (g != gcur) {
            atomicAdd(&Psum[gcur * DD + ch], sum);
            atomicAdd(&Psq[gcur * DD + ch], sq);
            atomicMax(&Pmaxk[gcur * DD + ch], fkey(mx));
            atomicMin(&Pmink[gcur * DD + ch], fkey(mn));
            sum = 0.f; sq = 0.f; mn = INFINITY; mx = -INFINITY; gcur = g;
        }
        sum += v; sq += v * v;
        mn = fminf(mn, v); mx = fmaxf(mx, v);
    }
    atomicAdd(&Psum[gcur * DD + ch], sum);
    atomicAdd(&Psq[gcur * DD + ch], sq);
    atomicMax(&Pmaxk[gcur * DD + ch], fkey(mx));
    atomicMin(&Pmink[gcur * DD + ch], fkey(mn));
}

// ------ BN1 finalize (fused, butterfly) + Hg + BN2: block=column, lane=graph
__global__ __launch_bounds__(64) void hg_kernel(
    const float* __restrict__ Psum, const float* __restrict__ Psq,
    const unsigned int* __restrict__ Pmaxk, const unsigned int* __restrict__ Pmink,
    const int* __restrict__ gstart,
    const float* __restrict__ g1, const float* __restrict__ be1,
    const float* __restrict__ g2, const float* __restrict__ be2,
    float* __restrict__ Hg) {
    int t = blockIdx.x;          // column 0..D3-1
    int g = threadIdx.x;         // graph 0..63
    int f = t / DD, c = t - f * DD;  // f: 0=avg 1=sum 2=max (block-uniform)
    float Sg = Psum[g * DD + c];
    float Qg = Psq[g * DD + c];
    float S = Sg, Q = Qg;
    for (int off = 32; off > 0; off >>= 1) {
        S += __shfl_xor(S, off);
        Q += __shfl_xor(Q, off);
    }
    float mu = S * (1.f / (float)NN);
    float var = Q * (1.f / (float)NN) - mu * mu;
    float sc = g1[c] * rsqrtf(var + EPSB);
    float bb = be1[c];
    float v;
    if (f == 2) {
        float mx = fdec(Pmaxk[g * DD + c]);
        float mn = fdec(Pmink[g * DD + c]);
        float raw = (sc >= 0.f) ? mx : mn;
        v = sc * (raw - mu) + bb;
    } else {
        float nf = (float)(gstart[g + 1] - gstart[g]);
        float hsum = sc * (Sg - nf * mu) + nf * bb;
        v = (f == 0) ? hsum / fmaxf(nf, 1.f) : hsum;
    }
    float s2 = v, ss2 = v * v;
    for (int off = 32; off > 0; off >>= 1) {
        s2 += __shfl_xor(s2, off);
        ss2 += __shfl_xor(ss2, off);
    }
    float m2 = s2 * (1.f / (float)GG);
    float var2 = ss2 * (1.f / (float)GG) - m2 * m2;
    float sc2 = g2[t] * rsqrtf(var2 + EPSB);
    Hg[g * D3 + t] = sc2 * (v - m2) + be2[t];
}

// ------ funnel head + log_softmax, ONE graph per block (64 blocks) ----------
__global__ __launch_bounds__(F1) void funnel_kernel(const float* __restrict__ Hg,
    const float* __restrict__ Wp1, const float* __restrict__ b1,
    const float* __restrict__ Wp2, const float* __restrict__ b2,
    const float* __restrict__ w3, const float* __restrict__ b3,
    float* __restrict__ out) {
    __shared__ float hg[D3];
    __shared__ float x1[F1];
    __shared__ float x2[F2];
    __shared__ float lg[NCLS];
    __shared__ float s_lse;
    int g = blockIdx.x, t = threadIdx.x;
    for (int i = t; i < D3; i += F1) hg[i] = Hg[g * D3 + i];
    __syncthreads();
    {
        float a = b1[t];
        const float4* W4 = (const float4*)Wp1;
        for (int k4 = 0; k4 < D3 / 4; k4++) {
            float4 w = W4[k4 * F1 + t];                 // coalesced
            const float4 h = *(const float4*)&hg[k4 * 4]; // broadcast
            a += w.x * h.x + w.y * h.y + w.z * h.z + w.w * h.w;
        }
        x1[t] = fmaxf(a, 0.f);
    }
    __syncthreads();
    if (t < F2) {
        float a = b2[t];
        const float4* W4 = (const float4*)Wp2;
        for (int k4 = 0; k4 < F1 / 4; k4++) {
            float4 w = W4[k4 * F2 + t];                 // coalesced
            const float4 h = *(const float4*)&x1[k4 * 4]; // broadcast
            a += w.x * h.x + w.y * h.y + w.z * h.z + w.w * h.w;
        }
        x2[t] = fmaxf(a, 0.f);
    }
    __syncthreads();
    if (t < NCLS) {
        float a = b3[t];
        const float4* wr = (const float4*)&w3[t * F2];
        const float4* h4 = (const float4*)x2;
        for (int k = 0; k < F2 / 4; k++) {
            float4 w = wr[k], h = h4[k];
            a += w.x * h.x + w.y * h.y + w.z * h.z + w.w * h.w;
        }
        lg[t] = a;
    }
    __syncthreads();
    if (t == 0) {
        float m = lg[0];
        for (int i = 1; i < NCLS; i++) m = fmaxf(m, lg[i]);
        float se = 0.f;
        for (int i = 0; i < NCLS; i++) se += expf(lg[i] - m);
        s_lse = m + logf(se);
    }
    __syncthreads();
    if (t < NCLS) out[g * NCLS + t] = lg[t] - s_lse;
}

// ---------------- launcher ----------------

extern "C" void kernel_launch(void* const* d_in, const int* in_sizes, int n_in,
                              void* d_out, int out_size, void* d_ws, size_t ws_size,
                              hipStream_t stream) {
    (void)in_sizes; (void)n_in; (void)out_size; (void)ws_size;
    const float* x     = (const float*)d_in[0];
    const int*   ei    = (const int*)d_in[1];    // int32 on device (harness contract)
    const int*   batch = (const int*)d_in[2];
    const float* W     = (const float*)d_in[3];
    const float* b     = (const float*)d_in[4];
    const float* u     = (const float*)d_in[5];
    const float* g1    = (const float*)d_in[6];
    const float* be1   = (const float*)d_in[7];
    const float* g2    = (const float*)d_in[8];
    const float* be2   = (const float*)d_in[9];
    const float* w1    = (const float*)d_in[10];
    const float* b1    = (const float*)d_in[11];
    const float* w2    = (const float*)d_in[12];
    const float* b2    = (const float*)d_in[13];
    const float* w3    = (const float*)d_in[14];
    const float* b3    = (const float*)d_in[15];
    float* out = (float*)d_out;
    char*  ws  = (char*)d_ws;

    // ---- workspace layout (bytes), ~7.5 MB ----
    int*            gstart  = (int*)(ws + 0);            //     512 (65 ints)
    int*            rowptr  = (int*)(ws + 512);          //   33024
    int*            deg     = (int*)(ws + 33536);        //   32768
    float*          dinv    = (float*)(ws + 66304);      //   32768
    float*          sig     = (float*)(ws + 99072);      //     256
    float*          Wp      = (float*)(ws + 99328);      //  147456
    float*          Psum    = (float*)(ws + 246784);     //   49152 (GG*DD)
    float*          Psq     = (float*)(ws + 295936);     //   49152
    unsigned int*   Pmaxk   = (unsigned int*)(ws + 345088); // 49152
    unsigned int*   Pmink   = (unsigned int*)(ws + 394240); // 49152
    float*          Hg      = (float*)(ws + 443392);     //  147456
    unsigned short* csr_col = (unsigned short*)(ws + 590848); // 524288
    float*          Wp1     = (float*)(ws + 1115136);    //  884736
    float*          Wp2     = (float*)(ws + 1999872);    //  294912
    unsigned short* pcnt    = (unsigned short*)(ws + 2294784); // 1048576 (u16)
    float*          Hx1     = (float*)(ws + 3343360);    // 2097152
    float*          Hx2     = (float*)(ws + 5440512);    // 2097152 -> end 7537664

    prep_kernel<<<326 + NB + 1, 1024, 0, stream>>>(W, u, w1, w2, batch, ei,
                                                   sig, gstart, pcnt, Wp, Wp1, Wp2,
                                                   (int*)Psum);
    offs_kernel<<<NN / 256, 256, 0, stream>>>(pcnt, deg, dinv);
    scatter_kernel<<<NB, 1024, 0, stream>>>(ei, deg, pcnt, rowptr, csr_col);
    // Hx1 = L @ x ; Hx2 = L @ Hx1   (compact [N,64], full-occupancy gathers)
    spmm_kernel<<<NN * 64 / 256, 256, 0, stream>>>(x, rowptr, csr_col, dinv, Hx1);
    spmm_kernel<<<NN * 64 / 256, 256, 0, stream>>>(Hx1, rowptr, csr_col, dinv, Hx2);
    gemm_pool_kernel<<<NN / 16, 384, 0, stream>>>(x, Hx1, Hx2, Wp, b, sig, batch,
                                                  Psum, Psq, Pmaxk, Pmink);
    hg_kernel<<<D3, 64, 0, stream>>>(Psum, Psq, Pmaxk, Pmink, gstart, g1, be1, g2, be2, Hg);
    funnel_kernel<<<GG, F1, 0, stream>>>(Hg, Wp1, b1, Wp2, b2, w3, b3, out);
}